// Round 5
// baseline (188.032 us; speedup 1.0000x reference)
//
#include <hip/hip_runtime.h>

// Problem constants (b=8, H=W=56, cin=64, cout=64, cmid=32, k=3, G=4, gc=16)
// ALL inputs and the output are float32. Internal GEMM in bf16 (absmax 0.125 vs thr 0.5275).
#define BATCH 8
#define PIX   3136          // 56*56
#define CIN8  512           // cin*8
#define CMID8 256
#define KDIM  512

typedef short short8 __attribute__((ext_vector_type(8)));
typedef float f32x4 __attribute__((ext_vector_type(4)));

__constant__ int c_perms[8][8] = {
    {0, 1, 2, 3, 4, 5, 6, 7},
    {3, 0, 1, 2, 5, 6, 7, 4},
    {2, 3, 0, 1, 6, 7, 4, 5},
    {1, 2, 3, 0, 7, 4, 5, 6},
    {4, 5, 6, 7, 0, 1, 2, 3},
    {5, 6, 7, 4, 3, 0, 1, 2},
    {6, 7, 4, 5, 2, 3, 0, 1},
};
__constant__ int c_perm7[8] = {7, 4, 5, 6, 1, 2, 3, 0};

// TAB[g][p]: source tap (ki'*3+kj') in wgt for output tap p=ki*3+kj  [verified R1]
__constant__ int c_tab[8][9] = {
    {0, 1, 2, 3, 4, 5, 6, 7, 8},
    {2, 5, 8, 1, 4, 7, 0, 3, 6},
    {8, 7, 6, 5, 4, 3, 2, 1, 0},
    {6, 3, 0, 7, 4, 1, 8, 5, 2},
    {2, 1, 0, 5, 4, 3, 8, 7, 6},
    {8, 5, 2, 7, 4, 1, 6, 3, 0},
    {6, 7, 8, 3, 4, 5, 0, 1, 2},
    {0, 3, 6, 1, 4, 7, 2, 5, 8},
};

__device__ __forceinline__ float bf2f(unsigned short u) {
    union { unsigned int i; float f; } v;
    v.i = ((unsigned int)u) << 16;
    return v.f;
}
__device__ __forceinline__ unsigned short f2bf(float f) {
    union { float f; unsigned int u; } v;
    v.f = f;
    unsigned int u = v.u;
    u += 0x7FFFu + ((u >> 16) & 1u);   // RNE
    return (unsigned short)(u >> 16);
}
__device__ __forceinline__ float bflo(unsigned int u) {
    union { unsigned int i; float f; } v; v.i = u << 16; return v.f;
}
__device__ __forceinline__ float bfhi(unsigned int u) {
    union { unsigned int i; float f; } v; v.i = u & 0xFFFF0000u; return v.f;
}

// async global->LDS, 16B per lane; LDS dest = uniform base + lane*16 [m97/m104]
__device__ __forceinline__ void gload_lds16(const unsigned short* g, unsigned short* l) {
    __builtin_amdgcn_global_load_lds(
        (const __attribute__((address_space(1))) unsigned int*)g,
        (__attribute__((address_space(3))) unsigned int*)l,
        16, 0, 0);
}

// ---------------------------------------------------------------------------
// K0a: fused convert + TRANSPOSE: x[b][k][p] f32 -> xbfT[b][p][k] bf16. (unchanged)
// ---------------------------------------------------------------------------
#define LDT 70
__global__ __launch_bounds__(256) void cvt_t_kernel(
    const float* __restrict__ x, unsigned short* __restrict__ xbfT)
{
    __shared__ unsigned short T[64 * LDT];
    const int flat = blockIdx.x;            // 8 * 49 * 8 = 3136 blocks
    const int kt = flat & 7;
    const int pt = (flat >> 3) % 49;
    const int b  = flat / (49 * 8);
    const int k0 = kt * 64, p0 = pt * 64;

    const float* xb = x + ((size_t)b * CIN8 + k0) * PIX + p0;
    const int kl = threadIdx.x >> 4;        // 0..15
    const int pl = (threadIdx.x & 15) * 4;  // 0..60
#pragma unroll
    for (int pass = 0; pass < 4; ++pass) {
        int kk = kl + pass * 16;
        float4 v = *(const float4*)(xb + (size_t)kk * PIX + pl);
        ushort2 lo = {f2bf(v.x), f2bf(v.y)};
        ushort2 hi = {f2bf(v.z), f2bf(v.w)};
        *(ushort2*)&T[kk * LDT + pl]     = lo;
        *(ushort2*)&T[kk * LDT + pl + 2] = hi;
    }
    __syncthreads();
    const int prow = threadIdx.x >> 2;        // 0..63
    const int kc8  = (threadIdx.x & 3) * 8;   // 0,8,16,24
    unsigned short* ob = xbfT + ((size_t)b * PIX + p0 + prow) * KDIM + k0;
#pragma unroll
    for (int pass = 0; pass < 2; ++pass) {
        int kk = kc8 + pass * 32;
        unsigned short tmp[8];
#pragma unroll
        for (int j = 0; j < 8; ++j) tmp[j] = T[(kk + j) * LDT + prow];
        *(uint4*)(ob + kk) = *(const uint4*)tmp;
    }
}

// ---------------------------------------------------------------------------
// K0b: build 768x512 permuted weight matrix in bf16, k-contiguous.
// Also zeroes the GN partial-sum buffer (512 floats) for the gemm atomics.
// ---------------------------------------------------------------------------
__global__ __launch_bounds__(256) void build_w_kernel(
    const float* __restrict__ w_v, const float* __restrict__ w1,
    unsigned short* __restrict__ Wbig, float* __restrict__ stats2)
{
    if (blockIdx.x < 2) stats2[blockIdx.x * 256 + threadIdx.x] = 0.f;

    int idx = blockIdx.x * 256 + threadIdx.x;     // 768*512 = 393216 exact
    int r = idx >> 9;
    int k = idx & 511;
    int i = k >> 3, f = k & 7;
    float v;
    if (r < 512) {
        int o = r >> 3, g = r & 7;
        int pf = (g < 7) ? c_perms[g][f] : c_perm7[f];
        v = w_v[(o * 64 + i) * 8 + pf];
    } else {
        int rr = r - 512;
        int o = rr >> 3, g = rr & 7;
        int pf = (g < 7) ? c_perms[g][f] : c_perm7[f];
        v = w1[(o * 64 + i) * 8 + pf];
    }
    Wbig[idx] = f2bf(v);
}

// ---------------------------------------------------------------------------
// K1: REVERTED to the R2 K-loop (best measured: 50.4us): 128x128 tile, BK=64,
// single-buffered LDS, __syncthreads drain per step. Pipelining grafts (dbuf
// R3, counted-vmcnt+lb(256,5) R4) both regressed (occupancy loss / spills).
// Kept from R3: XCD-chunked pt-major grid swizzle (FETCH 64->20MB) and the
// fused GN partial-sum epilogue. NEW: y1 stored as BF16 (stats still f32-exact
// from registers) -> -12.8MB gemm writes, -12.8MB final_fused reads.
// T2 XOR-swizzle (both-sides involution, rule #21): linear LDS dest,
// pre-swizzled global source chunk, read chunk ^= row&7. Conflicts = 0.
// ---------------------------------------------------------------------------
__global__ __launch_bounds__(256) void gemm_kernel(
    const unsigned short* __restrict__ xT,    // [25088][512]
    const unsigned short* __restrict__ Wbig,  // [768][512]
    unsigned short* __restrict__ xv,          // [8][512][3136] bf16
    unsigned short* __restrict__ y1b,         // [8][256][3136] bf16
    float* __restrict__ stats2)               // [8*32][2] raw sums {S, SS}
{
    __shared__ unsigned short Wt[128 * 64];   // 16 KB
    __shared__ unsigned short Xt[128 * 64];   // 16 KB

    // XCD-chunked swizzle (1176 = 8*147, bijective), then pt-major decode:
    // 6 consecutive logical blocks share one xT panel within an XCD's L2.
    const int swz = (blockIdx.x & 7) * 147 + (blockIdx.x >> 3);
    const int rt  = swz % 6;
    const int pt  = swz / 6;              // 0..195
    const int row0 = rt * 128;
    const int P0   = pt * 128;

    const int tid  = threadIdx.x;
    const int lane = tid & 63;
    const int wave = tid >> 6;
    const int wm   = wave & 1;          // M half
    const int wn   = wave >> 1;         // N half

    f32x4 acc[4][4];
#pragma unroll
    for (int i = 0; i < 4; ++i)
#pragma unroll
        for (int j = 0; j < 4; ++j) acc[i][j] = (f32x4){0.f, 0.f, 0.f, 0.f};

    // staging: each wave stages rows [wave*32, wave*32+32) of both tiles.
    // lane -> (row-in-8 lr, chunk lc); source k-chunk pre-swizzled by lr.
    const int lr  = lane >> 3;                 // 0..7
    const int lc  = lane & 7;                  // 0..7 (16B chunk)
    const int swc = ((lc ^ lr) * 8);           // pre-swizzled k offset (shorts)
    const unsigned short* wsrc = Wbig + (size_t)(row0 + wave * 32 + lr) * KDIM + swc;
    const unsigned short* xsrc = xT + (size_t)(P0 + wave * 32 + lr) * KDIM + swc;
    unsigned short* wdst = &Wt[(wave * 32) * 64];
    unsigned short* xdst = &Xt[(wave * 32) * 64];

    const int m16 = lane & 15;
    const int lq  = lane >> 4;                 // 0..3
    const int swr = m16 & 7;                   // read-side chunk xor

    for (int kc = 0; kc < 8; ++kc) {
        const int k0 = kc * 64;
#pragma unroll
        for (int i = 0; i < 4; ++i) {
            gload_lds16(wsrc + (size_t)i * 8 * KDIM + k0, wdst + i * 512);
            gload_lds16(xsrc + (size_t)i * 8 * KDIM + k0, xdst + i * 512);
        }
        __syncthreads();

#pragma unroll
        for (int kk = 0; kk < 2; ++kk) {
            const int ck = (((kk << 2) | lq) ^ swr) * 8;   // swizzled chunk offset
            short8 bfrag[4];
#pragma unroll
            for (int nt = 0; nt < 4; ++nt)
                bfrag[nt] = *(const short8*)&Xt[(wn * 64 + nt * 16 + m16) * 64 + ck];
#pragma unroll
            for (int mt = 0; mt < 4; ++mt) {
                short8 afrag = *(const short8*)&Wt[(wm * 64 + mt * 16 + m16) * 64 + ck];
#pragma unroll
                for (int nt = 0; nt < 4; ++nt)
                    acc[mt][nt] = __builtin_amdgcn_mfma_f32_16x16x32_bf16(
                        afrag, bfrag[nt], acc[mt][nt], 0, 0, 0);
            }
        }
        __syncthreads();
    }

    // ---- epilogue ----
    // 64 | 3136, so a wave's 64-col span never crosses a batch boundary.
    const int colw = P0 + wn * 64;
    const int bb   = colw / PIX;
    const int pq   = colw - bb * PIX;
    const int qm   = lq * 4;

    if (row0 < 512) {
        unsigned short* dst0 = xv + ((size_t)bb * CIN8) * PIX + pq + m16;
#pragma unroll
        for (int nt = 0; nt < 4; ++nt) {
            unsigned short* dst = dst0 + nt * 16;
#pragma unroll
            for (int mt = 0; mt < 4; ++mt) {
                const int m = row0 + wm * 64 + mt * 16 + qm;
#pragma unroll
                for (int r = 0; r < 4; ++r)
                    dst[(size_t)(m + r) * PIX] = f2bf(acc[mt][nt][r]);
            }
        }
    } else {
        unsigned short* dst0 = y1b + ((size_t)bb * CMID8) * PIX + pq + m16;
#pragma unroll
        for (int nt = 0; nt < 4; ++nt) {
            unsigned short* dst = dst0 + nt * 16;
#pragma unroll
            for (int mt = 0; mt < 4; ++mt) {
                const int m = (row0 - 512) + wm * 64 + mt * 16 + qm;
#pragma unroll
                for (int r = 0; r < 4; ++r)
                    dst[(size_t)(m + r) * PIX] = f2bf(acc[mt][nt][r]);
            }
        }
        // GN partial sums from EXACT f32 accumulators.
        // Channels mt*16+qm+r: lanes 0..31 hold group 2mt, lanes 32..63
        // group 2mt+1 (relative). Reduce each 32-lane half.
        const int gbase = ((row0 - 512) + wm * 64) >> 3;
#pragma unroll
        for (int mt = 0; mt < 4; ++mt) {
            float s = 0.f, ss = 0.f;
#pragma unroll
            for (int nt = 0; nt < 4; ++nt)
#pragma unroll
                for (int r = 0; r < 4; ++r) {
                    float v = acc[mt][nt][r];
                    s += v; ss += v * v;
                }
#pragma unroll
            for (int off = 1; off <= 16; off <<= 1) {
                s  += __shfl_xor(s, off);
                ss += __shfl_xor(ss, off);
            }
            if ((lane & 31) == 0) {
                const int g = gbase + 2 * mt + (lane >> 5);
                atomicAdd(&stats2[(bb * 32 + g) * 2],     s);
                atomicAdd(&stats2[(bb * 32 + g) * 2 + 1], ss);
            }
        }
    }
}

// ---------------------------------------------------------------------------
// K3+K4 FUSED: thread = quad of 4 pixels for one (b,g,gidx).
// Computes mean/rstd inline from the gemm's raw (S, SS) partial sums.
// y1 now read as BF16 (uint2 = 4 values). XCD-chunked swizzle (1024 = 8*128).
// ---------------------------------------------------------------------------
__global__ __launch_bounds__(256) void final_fused_kernel(
    const unsigned short* __restrict__ y1b, const float* __restrict__ stats2,
    const float* __restrict__ gamma, const float* __restrict__ beta,
    const float* __restrict__ w2, const float* __restrict__ b2,
    const unsigned short* __restrict__ xv,
    float* __restrict__ out)
{
    const int swz  = (blockIdx.x & 7) * 128 + (blockIdx.x >> 3);
    const int combo = swz >> 2;                  // b*32 + g*4 + gidx
    const int b    = combo >> 5;
    const int g    = (combo >> 2) & 7;
    const int gidx = combo & 3;

    __shared__ float w2s[9 * 32];   // permuted: w2s[tt*32+i] = w2[gidx,c_tab[g][tt],i]
    __shared__ float b2s9[9];
    __shared__ float scs[32], shs[32];
    const int tid = threadIdx.x;
    for (int i = tid; i < 288; i += 256) {
        int tt = i >> 5, ic = i & 31;
        w2s[i] = w2[(gidx * 9 + c_tab[g][tt]) * 32 + ic];
    }
    if (tid < 9) b2s9[tid] = b2[gidx * 9 + c_tab[g][tid]];
    if (tid < 32) {
        float S  = stats2[(b * 32 + tid) * 2];
        float SS = stats2[(b * 32 + tid) * 2 + 1];
        float mean = S * (1.f / 25088.f);
        float var  = SS * (1.f / 25088.f) - mean * mean;
        float rstd = rsqrtf(var + 1e-5f);
        float sc = rstd * gamma[tid * 8 + g];
        scs[tid] = sc;
        shs[tid] = beta[tid * 8 + g] - mean * sc;
    }
    __syncthreads();

    const int pp = (swz & 3) * 256 + tid;  // quad index
    if (pp >= 784) return;
    const int p0 = pp * 4;
    const int h  = p0 / 56;
    const int w0 = p0 % 56;                       // even, 0..52

    // ---- taps wt[px][tt] (already output-tap-permuted via w2s) ----
    float wt[4][9];
#pragma unroll
    for (int i = 0; i < 4; ++i)
#pragma unroll
        for (int tt = 0; tt < 9; ++tt) wt[i][tt] = b2s9[tt];

    const unsigned short* yb = y1b + ((size_t)b * CMID8 + g) * PIX + p0;
#pragma unroll 4
    for (int ic = 0; ic < 32; ++ic) {
        uint2 u = *(const uint2*)(yb + (size_t)(ic * 8) * PIX);
        float t0 = bflo(u.x) * scs[ic] + shs[ic]; t0 = t0 > 0.f ? t0 : 0.f;
        float t1 = bfhi(u.x) * scs[ic] + shs[ic]; t1 = t1 > 0.f ? t1 : 0.f;
        float t2 = bflo(u.y) * scs[ic] + shs[ic]; t2 = t2 > 0.f ? t2 : 0.f;
        float t3 = bfhi(u.y) * scs[ic] + shs[ic]; t3 = t3 > 0.f ? t3 : 0.f;
#pragma unroll
        for (int tt = 0; tt < 9; ++tt) {
            float wv = w2s[tt * 32 + ic];
            wt[0][tt] = fmaf(wv, t0, wt[0][tt]);
            wt[1][tt] = fmaf(wv, t1, wt[1][tt]);
            wt[2][tt] = fmaf(wv, t2, wt[2][tt]);
            wt[3][tt] = fmaf(wv, t3, wt[3][tt]);
        }
    }

    // ---- OOB zeroing + clamped row bases ----
    int rb[3];
#pragma unroll
    for (int ki = 0; ki < 3; ++ki) {
        int hh = h + ki - 1;
        bool rv = (hh >= 0) & (hh < 56);
        int hc = hh < 0 ? 0 : (hh > 55 ? 55 : hh);
        rb[ki] = hc * 56;
        if (!rv) {
#pragma unroll
            for (int i = 0; i < 4; ++i)
#pragma unroll
                for (int kj = 0; kj < 3; ++kj) wt[i][ki * 3 + kj] = 0.f;
        }
    }
#pragma unroll
    for (int i = 0; i < 4; ++i)
#pragma unroll
        for (int tt = 0; tt < 9; ++tt) {
            int ww = w0 + i + (tt % 3) - 1;
            if (ww < 0 || ww >= 56) wt[i][tt] = 0.f;
        }

    const int c0 = (w0 == 0) ? 0 : (w0 - 2);

    // ---- cc loop ----
    const unsigned short* xc = xv + ((size_t)b * CIN8 + gidx * 128 + g) * PIX;
    float* ob = out + ((size_t)b * CIN8 + gidx * 128 + g) * PIX + p0;
#pragma unroll 2
    for (int cc = 0; cc < 16; ++cc) {
        f32x4 a = (f32x4){0.f, 0.f, 0.f, 0.f};
#pragma unroll
        for (int ki = 0; ki < 3; ++ki) {
            const unsigned short* row = xc + rb[ki];
            unsigned int u0 = *(const unsigned int*)(row + c0);
            unsigned int u1 = *(const unsigned int*)(row + w0);
            unsigned int u2 = *(const unsigned int*)(row + w0 + 2);
            unsigned int u3 = *(const unsigned int*)(row + w0 + 4);
            // f[j] = value at ww = w0-2+j ; j=1..6
            float f1 = bfhi(u0);
            float f2 = bflo(u1), f3 = bfhi(u1);
            float f4 = bflo(u2), f5 = bfhi(u2);
            float f6 = bflo(u3);
            const int t0i = ki * 3;
            // px i, kj -> f[i+kj+1]
            a[0] = fmaf(wt[0][t0i + 0], f1, a[0]);
            a[0] = fmaf(wt[0][t0i + 1], f2, a[0]);
            a[0] = fmaf(wt[0][t0i + 2], f3, a[0]);
            a[1] = fmaf(wt[1][t0i + 0], f2, a[1]);
            a[1] = fmaf(wt[1][t0i + 1], f3, a[1]);
            a[1] = fmaf(wt[1][t0i + 2], f4, a[1]);
            a[2] = fmaf(wt[2][t0i + 0], f3, a[2]);
            a[2] = fmaf(wt[2][t0i + 1], f4, a[2]);
            a[2] = fmaf(wt[2][t0i + 2], f5, a[2]);
            a[3] = fmaf(wt[3][t0i + 0], f4, a[3]);
            a[3] = fmaf(wt[3][t0i + 1], f5, a[3]);
            a[3] = fmaf(wt[3][t0i + 2], f6, a[3]);
        }
        *(f32x4*)(ob + (size_t)cc * 8 * PIX) = a;
        xc += (size_t)8 * PIX;
    }
}

// ---------------------------------------------------------------------------
extern "C" void kernel_launch(void* const* d_in, const int* in_sizes, int n_in,
                              void* d_out, int out_size, void* d_ws, size_t ws_size,
                              hipStream_t stream) {
    (void)in_sizes; (void)n_in; (void)out_size; (void)ws_size;
    const float* x     = (const float*)d_in[0];
    const float* w_v   = (const float*)d_in[1];
    const float* w1    = (const float*)d_in[2];
    const float* gamma = (const float*)d_in[3];
    const float* beta  = (const float*)d_in[4];
    const float* w2    = (const float*)d_in[5];
    const float* b2    = (const float*)d_in[6];
    float* out = (float*)d_out;

    char* ws = (char*)d_ws;
    unsigned short* Wbig = (unsigned short*)ws;                    //    786,432 B
    unsigned short* xbfT = (unsigned short*)(ws + 786432);         // 25,690,112 B  [b][p][k]
    unsigned short* xv   = (unsigned short*)(ws + 26476544);       // 25,690,112 B  [b][ch][p]
    unsigned short* y1b  = (unsigned short*)(ws + 52166656);       // 12,845,056 B  bf16
    float* stats2 = (float*)(ws + 65011712);                       //      2,048 B

    cvt_t_kernel<<<3136, 256, 0, stream>>>(x, xbfT);
    build_w_kernel<<<1536, 256, 0, stream>>>(w_v, w1, Wbig, stats2);
    gemm_kernel<<<1176, 256, 0, stream>>>(xbfT, Wbig, xv, y1b, stats2);
    final_fused_kernel<<<256 * 4, 256, 0, stream>>>(
        y1b, stats2, gamma, beta, w2, b2, xv, out);
}

// Round 6
// 160.297 us; speedup vs baseline: 1.1730x; 1.1730x over previous
//
#include <hip/hip_runtime.h>

// Problem constants (b=8, H=W=56, cin=64, cout=64, cmid=32, k=3, G=4, gc=16)
// ALL inputs and the output are float32. Internal GEMM in bf16 (absmax 0.125 vs thr 0.5275).
#define BATCH 8
#define PIX   3136          // 56*56
#define CIN8  512           // cin*8
#define CMID8 256
#define KDIM  512

typedef short short8 __attribute__((ext_vector_type(8)));
typedef float f32x4 __attribute__((ext_vector_type(4)));

__constant__ int c_perms[8][8] = {
    {0, 1, 2, 3, 4, 5, 6, 7},
    {3, 0, 1, 2, 5, 6, 7, 4},
    {2, 3, 0, 1, 6, 7, 4, 5},
    {1, 2, 3, 0, 7, 4, 5, 6},
    {4, 5, 6, 7, 0, 1, 2, 3},
    {5, 6, 7, 4, 3, 0, 1, 2},
    {6, 7, 4, 5, 2, 3, 0, 1},
};
__constant__ int c_perm7[8] = {7, 4, 5, 6, 1, 2, 3, 0};

// TAB[g][p]: source tap (ki'*3+kj') in wgt for output tap p=ki*3+kj  [verified R1]
__constant__ int c_tab[8][9] = {
    {0, 1, 2, 3, 4, 5, 6, 7, 8},
    {2, 5, 8, 1, 4, 7, 0, 3, 6},
    {8, 7, 6, 5, 4, 3, 2, 1, 0},
    {6, 3, 0, 7, 4, 1, 8, 5, 2},
    {2, 1, 0, 5, 4, 3, 8, 7, 6},
    {8, 5, 2, 7, 4, 1, 6, 3, 0},
    {6, 7, 8, 3, 4, 5, 0, 1, 2},
    {0, 3, 6, 1, 4, 7, 2, 5, 8},
};

__device__ __forceinline__ float bf2f(unsigned short u) {
    union { unsigned int i; float f; } v;
    v.i = ((unsigned int)u) << 16;
    return v.f;
}
__device__ __forceinline__ unsigned short f2bf(float f) {
    union { float f; unsigned int u; } v;
    v.f = f;
    unsigned int u = v.u;
    u += 0x7FFFu + ((u >> 16) & 1u);   // RNE
    return (unsigned short)(u >> 16);
}
__device__ __forceinline__ float bflo(unsigned int u) {
    union { unsigned int i; float f; } v; v.i = u << 16; return v.f;
}
__device__ __forceinline__ float bfhi(unsigned int u) {
    union { unsigned int i; float f; } v; v.i = u & 0xFFFF0000u; return v.f;
}

// async global->LDS, 16B per lane; LDS dest = uniform base + lane*16 [m97/m104]
__device__ __forceinline__ void gload_lds16(const unsigned short* g, unsigned short* l) {
    __builtin_amdgcn_global_load_lds(
        (const __attribute__((address_space(1))) unsigned int*)g,
        (__attribute__((address_space(3))) unsigned int*)l,
        16, 0, 0);
}

// ---------------------------------------------------------------------------
// K0a: fused convert + TRANSPOSE: x[b][k][p] f32 -> xbfT[b][p][k] bf16. (unchanged)
// ---------------------------------------------------------------------------
#define LDT 70
__global__ __launch_bounds__(256) void cvt_t_kernel(
    const float* __restrict__ x, unsigned short* __restrict__ xbfT)
{
    __shared__ unsigned short T[64 * LDT];
    const int flat = blockIdx.x;            // 8 * 49 * 8 = 3136 blocks
    const int kt = flat & 7;
    const int pt = (flat >> 3) % 49;
    const int b  = flat / (49 * 8);
    const int k0 = kt * 64, p0 = pt * 64;

    const float* xb = x + ((size_t)b * CIN8 + k0) * PIX + p0;
    const int kl = threadIdx.x >> 4;        // 0..15
    const int pl = (threadIdx.x & 15) * 4;  // 0..60
#pragma unroll
    for (int pass = 0; pass < 4; ++pass) {
        int kk = kl + pass * 16;
        float4 v = *(const float4*)(xb + (size_t)kk * PIX + pl);
        ushort2 lo = {f2bf(v.x), f2bf(v.y)};
        ushort2 hi = {f2bf(v.z), f2bf(v.w)};
        *(ushort2*)&T[kk * LDT + pl]     = lo;
        *(ushort2*)&T[kk * LDT + pl + 2] = hi;
    }
    __syncthreads();
    const int prow = threadIdx.x >> 2;        // 0..63
    const int kc8  = (threadIdx.x & 3) * 8;   // 0,8,16,24
    unsigned short* ob = xbfT + ((size_t)b * PIX + p0 + prow) * KDIM + k0;
#pragma unroll
    for (int pass = 0; pass < 2; ++pass) {
        int kk = kc8 + pass * 32;
        unsigned short tmp[8];
#pragma unroll
        for (int j = 0; j < 8; ++j) tmp[j] = T[(kk + j) * LDT + prow];
        *(uint4*)(ob + kk) = *(const uint4*)tmp;
    }
}

// ---------------------------------------------------------------------------
// K0b: build 768x512 permuted weight matrix in bf16, k-contiguous.
// Also zeroes the GN partial-sum buffer (512 floats) for the gemm atomics.
// ---------------------------------------------------------------------------
__global__ __launch_bounds__(256) void build_w_kernel(
    const float* __restrict__ w_v, const float* __restrict__ w1,
    unsigned short* __restrict__ Wbig, float* __restrict__ stats2)
{
    if (blockIdx.x < 2) stats2[blockIdx.x * 256 + threadIdx.x] = 0.f;

    int idx = blockIdx.x * 256 + threadIdx.x;     // 768*512 = 393216 exact
    int r = idx >> 9;
    int k = idx & 511;
    int i = k >> 3, f = k & 7;
    float v;
    if (r < 512) {
        int o = r >> 3, g = r & 7;
        int pf = (g < 7) ? c_perms[g][f] : c_perm7[f];
        v = w_v[(o * 64 + i) * 8 + pf];
    } else {
        int rr = r - 512;
        int o = rr >> 3, g = rr & 7;
        int pf = (g < 7) ? c_perms[g][f] : c_perm7[f];
        v = w1[(o * 64 + i) * 8 + pf];
    }
    Wbig[idx] = f2bf(v);
}

// ---------------------------------------------------------------------------
// K1: R2 K-loop (best measured): 128x128 tile, BK=64, single-buffered LDS,
// __syncthreads drain per step. NEW this round: __launch_bounds__(256,4)
// caps VGPR at 128 (R5's bf16 epilogue pushed the allocator to 160 VGPR ->
// 3 waves/SIMD -> gemm 50.4->59.9us; the R2 loop lived in 124). Any squeeze
// spills only in the one-shot epilogue, not the K-loop.
// Kept: XCD-chunked pt-major grid swizzle (FETCH 64->16MB), fused GN partial
// sums, y1 stored BF16 (WRITE 52->38MB, stats still f32-exact from registers),
// T2 XOR-swizzle (both-sides involution, rule #21) -> 0 conflicts.
// ---------------------------------------------------------------------------
__global__ __launch_bounds__(256, 4) void gemm_kernel(
    const unsigned short* __restrict__ xT,    // [25088][512]
    const unsigned short* __restrict__ Wbig,  // [768][512]
    unsigned short* __restrict__ xv,          // [8][512][3136] bf16
    unsigned short* __restrict__ y1b,         // [8][256][3136] bf16
    float* __restrict__ stats2)               // [8*32][2] raw sums {S, SS}
{
    __shared__ unsigned short Wt[128 * 64];   // 16 KB
    __shared__ unsigned short Xt[128 * 64];   // 16 KB

    // XCD-chunked swizzle (1176 = 8*147, bijective), then pt-major decode:
    // 6 consecutive logical blocks share one xT panel within an XCD's L2.
    const int swz = (blockIdx.x & 7) * 147 + (blockIdx.x >> 3);
    const int rt  = swz % 6;
    const int pt  = swz / 6;              // 0..195
    const int row0 = rt * 128;
    const int P0   = pt * 128;

    const int tid  = threadIdx.x;
    const int lane = tid & 63;
    const int wave = tid >> 6;
    const int wm   = wave & 1;          // M half
    const int wn   = wave >> 1;         // N half

    f32x4 acc[4][4];
#pragma unroll
    for (int i = 0; i < 4; ++i)
#pragma unroll
        for (int j = 0; j < 4; ++j) acc[i][j] = (f32x4){0.f, 0.f, 0.f, 0.f};

    // staging: each wave stages rows [wave*32, wave*32+32) of both tiles.
    // lane -> (row-in-8 lr, chunk lc); source k-chunk pre-swizzled by lr.
    const int lr  = lane >> 3;                 // 0..7
    const int lc  = lane & 7;                  // 0..7 (16B chunk)
    const int swc = ((lc ^ lr) * 8);           // pre-swizzled k offset (shorts)
    const unsigned short* wsrc = Wbig + (size_t)(row0 + wave * 32 + lr) * KDIM + swc;
    const unsigned short* xsrc = xT + (size_t)(P0 + wave * 32 + lr) * KDIM + swc;
    unsigned short* wdst = &Wt[(wave * 32) * 64];
    unsigned short* xdst = &Xt[(wave * 32) * 64];

    const int m16 = lane & 15;
    const int lq  = lane >> 4;                 // 0..3
    const int swr = m16 & 7;                   // read-side chunk xor

    for (int kc = 0; kc < 8; ++kc) {
        const int k0 = kc * 64;
#pragma unroll
        for (int i = 0; i < 4; ++i) {
            gload_lds16(wsrc + (size_t)i * 8 * KDIM + k0, wdst + i * 512);
            gload_lds16(xsrc + (size_t)i * 8 * KDIM + k0, xdst + i * 512);
        }
        __syncthreads();

#pragma unroll
        for (int kk = 0; kk < 2; ++kk) {
            const int ck = (((kk << 2) | lq) ^ swr) * 8;   // swizzled chunk offset
            short8 bfrag[4];
#pragma unroll
            for (int nt = 0; nt < 4; ++nt)
                bfrag[nt] = *(const short8*)&Xt[(wn * 64 + nt * 16 + m16) * 64 + ck];
#pragma unroll
            for (int mt = 0; mt < 4; ++mt) {
                short8 afrag = *(const short8*)&Wt[(wm * 64 + mt * 16 + m16) * 64 + ck];
#pragma unroll
                for (int nt = 0; nt < 4; ++nt)
                    acc[mt][nt] = __builtin_amdgcn_mfma_f32_16x16x32_bf16(
                        afrag, bfrag[nt], acc[mt][nt], 0, 0, 0);
            }
        }
        __syncthreads();
    }

    // ---- epilogue ----
    // 64 | 3136, so a wave's 64-col span never crosses a batch boundary.
    const int colw = P0 + wn * 64;
    const int bb   = colw / PIX;
    const int pq   = colw - bb * PIX;
    const int qm   = lq * 4;

    if (row0 < 512) {
        unsigned short* dst0 = xv + ((size_t)bb * CIN8) * PIX + pq + m16;
#pragma unroll
        for (int nt = 0; nt < 4; ++nt) {
            unsigned short* dst = dst0 + nt * 16;
#pragma unroll
            for (int mt = 0; mt < 4; ++mt) {
                const int m = row0 + wm * 64 + mt * 16 + qm;
#pragma unroll
                for (int r = 0; r < 4; ++r)
                    dst[(size_t)(m + r) * PIX] = f2bf(acc[mt][nt][r]);
            }
        }
    } else {
        unsigned short* dst0 = y1b + ((size_t)bb * CMID8) * PIX + pq + m16;
#pragma unroll
        for (int nt = 0; nt < 4; ++nt) {
            unsigned short* dst = dst0 + nt * 16;
#pragma unroll
            for (int mt = 0; mt < 4; ++mt) {
                const int m = (row0 - 512) + wm * 64 + mt * 16 + qm;
#pragma unroll
                for (int r = 0; r < 4; ++r)
                    dst[(size_t)(m + r) * PIX] = f2bf(acc[mt][nt][r]);
            }
        }
        // GN partial sums from EXACT f32 accumulators.
        // Channels mt*16+qm+r: lanes 0..31 hold group 2mt, lanes 32..63
        // group 2mt+1 (relative). Reduce each 32-lane half.
        const int gbase = ((row0 - 512) + wm * 64) >> 3;
#pragma unroll
        for (int mt = 0; mt < 4; ++mt) {
            float s = 0.f, ss = 0.f;
#pragma unroll
            for (int nt = 0; nt < 4; ++nt)
#pragma unroll
                for (int r = 0; r < 4; ++r) {
                    float v = acc[mt][nt][r];
                    s += v; ss += v * v;
                }
#pragma unroll
            for (int off = 1; off <= 16; off <<= 1) {
                s  += __shfl_xor(s, off);
                ss += __shfl_xor(ss, off);
            }
            if ((lane & 31) == 0) {
                const int g = gbase + 2 * mt + (lane >> 5);
                atomicAdd(&stats2[(bb * 32 + g) * 2],     s);
                atomicAdd(&stats2[(bb * 32 + g) * 2 + 1], ss);
            }
        }
    }
}

// ---------------------------------------------------------------------------
// K3+K4 FUSED: thread = quad of 4 pixels for one (b,g,gidx).
// Computes mean/rstd inline from the gemm's raw (S, SS) partial sums.
// y1 read as BF16 (uint2 = 4 values). XCD-chunked swizzle (1024 = 8*128).
// ---------------------------------------------------------------------------
__global__ __launch_bounds__(256) void final_fused_kernel(
    const unsigned short* __restrict__ y1b, const float* __restrict__ stats2,
    const float* __restrict__ gamma, const float* __restrict__ beta,
    const float* __restrict__ w2, const float* __restrict__ b2,
    const unsigned short* __restrict__ xv,
    float* __restrict__ out)
{
    const int swz  = (blockIdx.x & 7) * 128 + (blockIdx.x >> 3);
    const int combo = swz >> 2;                  // b*32 + g*4 + gidx
    const int b    = combo >> 5;
    const int g    = (combo >> 2) & 7;
    const int gidx = combo & 3;

    __shared__ float w2s[9 * 32];   // permuted: w2s[tt*32+i] = w2[gidx,c_tab[g][tt],i]
    __shared__ float b2s9[9];
    __shared__ float scs[32], shs[32];
    const int tid = threadIdx.x;
    for (int i = tid; i < 288; i += 256) {
        int tt = i >> 5, ic = i & 31;
        w2s[i] = w2[(gidx * 9 + c_tab[g][tt]) * 32 + ic];
    }
    if (tid < 9) b2s9[tid] = b2[gidx * 9 + c_tab[g][tid]];
    if (tid < 32) {
        float S  = stats2[(b * 32 + tid) * 2];
        float SS = stats2[(b * 32 + tid) * 2 + 1];
        float mean = S * (1.f / 25088.f);
        float var  = SS * (1.f / 25088.f) - mean * mean;
        float rstd = rsqrtf(var + 1e-5f);
        float sc = rstd * gamma[tid * 8 + g];
        scs[tid] = sc;
        shs[tid] = beta[tid * 8 + g] - mean * sc;
    }
    __syncthreads();

    const int pp = (swz & 3) * 256 + tid;  // quad index
    if (pp >= 784) return;
    const int p0 = pp * 4;
    const int h  = p0 / 56;
    const int w0 = p0 % 56;                       // even, 0..52

    // ---- taps wt[px][tt] (already output-tap-permuted via w2s) ----
    float wt[4][9];
#pragma unroll
    for (int i = 0; i < 4; ++i)
#pragma unroll
        for (int tt = 0; tt < 9; ++tt) wt[i][tt] = b2s9[tt];

    const unsigned short* yb = y1b + ((size_t)b * CMID8 + g) * PIX + p0;
#pragma unroll 4
    for (int ic = 0; ic < 32; ++ic) {
        uint2 u = *(const uint2*)(yb + (size_t)(ic * 8) * PIX);
        float t0 = bflo(u.x) * scs[ic] + shs[ic]; t0 = t0 > 0.f ? t0 : 0.f;
        float t1 = bfhi(u.x) * scs[ic] + shs[ic]; t1 = t1 > 0.f ? t1 : 0.f;
        float t2 = bflo(u.y) * scs[ic] + shs[ic]; t2 = t2 > 0.f ? t2 : 0.f;
        float t3 = bfhi(u.y) * scs[ic] + shs[ic]; t3 = t3 > 0.f ? t3 : 0.f;
#pragma unroll
        for (int tt = 0; tt < 9; ++tt) {
            float wv = w2s[tt * 32 + ic];
            wt[0][tt] = fmaf(wv, t0, wt[0][tt]);
            wt[1][tt] = fmaf(wv, t1, wt[1][tt]);
            wt[2][tt] = fmaf(wv, t2, wt[2][tt]);
            wt[3][tt] = fmaf(wv, t3, wt[3][tt]);
        }
    }

    // ---- OOB zeroing + clamped row bases ----
    int rb[3];
#pragma unroll
    for (int ki = 0; ki < 3; ++ki) {
        int hh = h + ki - 1;
        bool rv = (hh >= 0) & (hh < 56);
        int hc = hh < 0 ? 0 : (hh > 55 ? 55 : hh);
        rb[ki] = hc * 56;
        if (!rv) {
#pragma unroll
            for (int i = 0; i < 4; ++i)
#pragma unroll
                for (int kj = 0; kj < 3; ++kj) wt[i][ki * 3 + kj] = 0.f;
        }
    }
#pragma unroll
    for (int i = 0; i < 4; ++i)
#pragma unroll
        for (int tt = 0; tt < 9; ++tt) {
            int ww = w0 + i + (tt % 3) - 1;
            if (ww < 0 || ww >= 56) wt[i][tt] = 0.f;
        }

    const int c0 = (w0 == 0) ? 0 : (w0 - 2);

    // ---- cc loop ----
    const unsigned short* xc = xv + ((size_t)b * CIN8 + gidx * 128 + g) * PIX;
    float* ob = out + ((size_t)b * CIN8 + gidx * 128 + g) * PIX + p0;
#pragma unroll 2
    for (int cc = 0; cc < 16; ++cc) {
        f32x4 a = (f32x4){0.f, 0.f, 0.f, 0.f};
#pragma unroll
        for (int ki = 0; ki < 3; ++ki) {
            const unsigned short* row = xc + rb[ki];
            unsigned int u0 = *(const unsigned int*)(row + c0);
            unsigned int u1 = *(const unsigned int*)(row + w0);
            unsigned int u2 = *(const unsigned int*)(row + w0 + 2);
            unsigned int u3 = *(const unsigned int*)(row + w0 + 4);
            // f[j] = value at ww = w0-2+j ; j=1..6
            float f1 = bfhi(u0);
            float f2 = bflo(u1), f3 = bfhi(u1);
            float f4 = bflo(u2), f5 = bfhi(u2);
            float f6 = bflo(u3);
            const int t0i = ki * 3;
            // px i, kj -> f[i+kj+1]
            a[0] = fmaf(wt[0][t0i + 0], f1, a[0]);
            a[0] = fmaf(wt[0][t0i + 1], f2, a[0]);
            a[0] = fmaf(wt[0][t0i + 2], f3, a[0]);
            a[1] = fmaf(wt[1][t0i + 0], f2, a[1]);
            a[1] = fmaf(wt[1][t0i + 1], f3, a[1]);
            a[1] = fmaf(wt[1][t0i + 2], f4, a[1]);
            a[2] = fmaf(wt[2][t0i + 0], f3, a[2]);
            a[2] = fmaf(wt[2][t0i + 1], f4, a[2]);
            a[2] = fmaf(wt[2][t0i + 2], f5, a[2]);
            a[3] = fmaf(wt[3][t0i + 0], f4, a[3]);
            a[3] = fmaf(wt[3][t0i + 1], f5, a[3]);
            a[3] = fmaf(wt[3][t0i + 2], f6, a[3]);
        }
        *(f32x4*)(ob + (size_t)cc * 8 * PIX) = a;
        xc += (size_t)8 * PIX;
    }
}

// ---------------------------------------------------------------------------
extern "C" void kernel_launch(void* const* d_in, const int* in_sizes, int n_in,
                              void* d_out, int out_size, void* d_ws, size_t ws_size,
                              hipStream_t stream) {
    (void)in_sizes; (void)n_in; (void)out_size; (void)ws_size;
    const float* x     = (const float*)d_in[0];
    const float* w_v   = (const float*)d_in[1];
    const float* w1    = (const float*)d_in[2];
    const float* gamma = (const float*)d_in[3];
    const float* beta  = (const float*)d_in[4];
    const float* w2    = (const float*)d_in[5];
    const float* b2    = (const float*)d_in[6];
    float* out = (float*)d_out;

    char* ws = (char*)d_ws;
    unsigned short* Wbig = (unsigned short*)ws;                    //    786,432 B
    unsigned short* xbfT = (unsigned short*)(ws + 786432);         // 25,690,112 B  [b][p][k]
    unsigned short* xv   = (unsigned short*)(ws + 26476544);       // 25,690,112 B  [b][ch][p]
    unsigned short* y1b  = (unsigned short*)(ws + 52166656);       // 12,845,056 B  bf16
    float* stats2 = (float*)(ws + 65011712);                       //      2,048 B

    cvt_t_kernel<<<3136, 256, 0, stream>>>(x, xbfT);
    build_w_kernel<<<1536, 256, 0, stream>>>(w_v, w1, Wbig, stats2);
    gemm_kernel<<<1176, 256, 0, stream>>>(xbfT, Wbig, xv, y1b, stats2);
    final_fused_kernel<<<256 * 4, 256, 0, stream>>>(
        y1b, stats2, gamma, beta, w2, b2, xv, out);
}